// Round 8
// baseline (63.278 us; speedup 1.0000x reference)
//
#include <hip/hip_runtime.h>

#define HH 56
#define WW 56
#define HWSZ 3136
#define KS 7
#define KK 49

#define XSTR 520   // x_lds: shorts per c-block row (64px*8c + 8 pad), 1040 B, 16B-aligned
#define TSTR 72    // t_lds row stride in shorts (144 B, 16B-aligned)

typedef __attribute__((ext_vector_type(8))) short short8;
typedef __attribute__((ext_vector_type(4))) float f32x4;

__device__ inline unsigned short f2bf(float f) {
    unsigned u = __builtin_bit_cast(unsigned, f);
    u += 0x7FFF + ((u >> 16) & 1);          // RNE
    return (unsigned short)(u >> 16);
}
__device__ inline unsigned pk2(float a, float b) {
    return (unsigned)f2bf(a) | ((unsigned)f2bf(b) << 16);
}
__device__ inline float bflo(unsigned u) { return __builtin_bit_cast(float, u << 16); }
__device__ inline float bfhi(unsigned u) { return __builtin_bit_cast(float, u & 0xFFFF0000u); }

// ---- single fused kernel: stage x -> GEMM1 (t) -> GEMM2 (wgt) -> dynamic conv ----
// grid 1792 = 8 group-pairs (XCD-pinned) x 224 (b,h); block 256 (4 waves)
__global__ __launch_bounds__(256) void fused_dynconv(
    const float* __restrict__ x, const float* __restrict__ y,
    const float* __restrict__ w1, const float* __restrict__ gamma,
    const float* __restrict__ beta, const float* __restrict__ mean,
    const float* __restrict__ var, const float* __restrict__ w2,
    const float* __restrict__ b2, float* __restrict__ out)
{
    __shared__ __align__(16) unsigned short lds[32 * XSTR + 64 * TSTR]; // 42.5 KB
    unsigned short* xls = lds;              // [cblk 32][64 px][8 c]
    unsigned short* tls = lds + 32 * XSTR;  // [64 px][64 o] stride TSTR
    unsigned short* wgt = lds;              // [2 gl][52 kk][68 px-stride]; aliases xls

    const int tid = threadIdx.x;
    const int gp = blockIdx.x & 7;          // XCD-pinned group-pair
    const int bh = blockIdx.x >> 3;         // 0..223
    const int b = bh / HH, h = bh - b * HH;
    const int hw0 = h * WW;

    // ---- phase 0: stage x[64px][256c] -> bf16 LDS (256B-coalesced loads) ----
    {
        const int pl = tid & 63, cq = tid >> 6;         // px, c-quarter
        const int hwc = min(hw0 + pl, HWSZ - 1);        // clamp image tail (h=55 spill)
        const float* xb = x + (size_t)b * 256 * HWSZ + hwc;
        #pragma unroll
        for (int ps = 0; ps < 8; ++ps) {
            const int cb = ps * 4 + cq;
            const int c0 = cb * 8;
            unsigned u[4];
            #pragma unroll
            for (int j = 0; j < 4; ++j) {
                float va = xb[(size_t)(c0 + 2 * j) * HWSZ];
                float vb = xb[(size_t)(c0 + 2 * j + 1) * HWSZ];
                u[j] = pk2(va, vb);
            }
            *(uint4*)&xls[cb * XSTR + pl * 8] = make_uint4(u[0], u[1], u[2], u[3]);
        }
    }

    const int lane = tid & 63, wv = tid >> 6;
    const int m = lane & 15, q = lane >> 4;

    // A-fragments for GEMM1 from global w1 (L1/L2-hot): o = wv*16+m, c = ks*32+q*8+j
    short8 af[8];
    {
        const float* wrow = w1 + (wv * 16 + m) * 256 + q * 8;
        #pragma unroll
        for (int ks = 0; ks < 8; ++ks) {
            float4 f0 = *(const float4*)(wrow + ks * 32);
            float4 f1 = *(const float4*)(wrow + ks * 32 + 4);
            short8 s;
            s[0] = (short)f2bf(f0.x); s[1] = (short)f2bf(f0.y);
            s[2] = (short)f2bf(f0.z); s[3] = (short)f2bf(f0.w);
            s[4] = (short)f2bf(f1.x); s[5] = (short)f2bf(f1.y);
            s[6] = (short)f2bf(f1.z); s[7] = (short)f2bf(f1.w);
            af[ks] = s;
        }
    }
    __syncthreads();

    // ---- phase 1: GEMM1  t[px][o] = relu(BN(x @ w1^T)), wave wv owns o-tile ----
    #pragma unroll
    for (int nt = 0; nt < 4; ++nt) {
        f32x4 acc = {0.f, 0.f, 0.f, 0.f};
        #pragma unroll
        for (int ks = 0; ks < 8; ++ks) {
            short8 bfr = *(const short8*)&xls[(ks * 4 + q) * XSTR + (nt * 16 + m) * 8];
            acc = __builtin_amdgcn_mfma_f32_16x16x32_bf16(af[ks], bfr, acc, 0, 0, 0);
        }
        // D: col(lane&15)=px, row((lane>>4)*4+j)=o — verified layout
        const int ob = wv * 16 + q * 4;
        float4 g4 = *(const float4*)&gamma[ob];
        float4 v4 = *(const float4*)&var[ob];
        float4 m4 = *(const float4*)&mean[ob];
        float4 b4 = *(const float4*)&beta[ob];
        float gg[4] = {g4.x, g4.y, g4.z, g4.w};
        float vv[4] = {v4.x, v4.y, v4.z, v4.w};
        float mm[4] = {m4.x, m4.y, m4.z, m4.w};
        float bb[4] = {b4.x, b4.y, b4.z, b4.w};
        float r[4];
        #pragma unroll
        for (int j = 0; j < 4; ++j) {
            float sc = gg[j] * rsqrtf(vv[j] + 1e-5f);
            float sh = bb[j] - mm[j] * sc;
            float val = acc[j] * sc + sh;
            r[j] = val > 0.f ? val : 0.f;
        }
        *(uint2*)&tls[(nt * 16 + m) * TSTR + ob] = make_uint2(pk2(r[0], r[1]), pk2(r[2], r[3]));
    }
    __syncthreads();

    // ---- phase 2: GEMM2  wgt[gl][kk][px] = sum_k t[px][k] * w2[g][kk][k] + b2 ----
    {
        const int pt = wv;                  // wave = pixel-tile, both groups
        const unsigned short* tp = tls + (pt * 16 + m) * TSTR + q * 8;
        short8 a0 = *(const short8*)tp;            // k = q*8 + 0..7
        short8 a1 = *(const short8*)(tp + 32);     // k = 32 + q*8 + 0..7
        #pragma unroll
        for (int it = 0; it < 2; ++it) {
            const int g = gp * 2 + it;
            f32x4 acc[4];
            #pragma unroll
            for (int mt = 0; mt < 4; ++mt) { acc[mt][0]=0.f; acc[mt][1]=0.f; acc[mt][2]=0.f; acc[mt][3]=0.f; }
            #pragma unroll
            for (int mt = 0; mt < 4; ++mt) {
                const int rc = min(mt * 16 + m, KK - 1);      // clamp pad rows (cols unused)
                const float* w2r = w2 + (size_t)(g * KK + rc) * 64 + q * 8;
                float4 f0 = *(const float4*)(w2r);
                float4 f1 = *(const float4*)(w2r + 4);
                float4 f2 = *(const float4*)(w2r + 32);
                float4 f3 = *(const float4*)(w2r + 36);
                short8 b0, b1;
                b0[0]=(short)f2bf(f0.x); b0[1]=(short)f2bf(f0.y); b0[2]=(short)f2bf(f0.z); b0[3]=(short)f2bf(f0.w);
                b0[4]=(short)f2bf(f1.x); b0[5]=(short)f2bf(f1.y); b0[6]=(short)f2bf(f1.z); b0[7]=(short)f2bf(f1.w);
                b1[0]=(short)f2bf(f2.x); b1[1]=(short)f2bf(f2.y); b1[2]=(short)f2bf(f2.z); b1[3]=(short)f2bf(f2.w);
                b1[4]=(short)f2bf(f3.x); b1[5]=(short)f2bf(f3.y); b1[6]=(short)f2bf(f3.z); b1[7]=(short)f2bf(f3.w);
                acc[mt] = __builtin_amdgcn_mfma_f32_16x16x32_bf16(a0, b0, acc[mt], 0, 0, 0);
                acc[mt] = __builtin_amdgcn_mfma_f32_16x16x32_bf16(a1, b1, acc[mt], 0, 0, 0);
            }
            // D: col(kk)=lane&15, row(px)=(lane>>4)*4+j — verified layout
            #pragma unroll
            for (int mt = 0; mt < 4; ++mt) {
                const int kk = mt * 16 + m;
                if (kk < 52) {
                    float bv = (kk < KK) ? b2[g * KK + kk] : 0.f;
                    f32x4 v = acc[mt];
                    const int pxb = pt * 16 + q * 4;
                    *(uint2*)&wgt[(it * 52 + kk) * 68 + pxb] =
                        make_uint2(pk2(v[0] + bv, v[1] + bv), pk2(v[2] + bv, v[3] + bv));
                }
            }
        }
    }
    __syncthreads();

    // ---- phase 3: conv, 2cc x 4px per thread, 1-row-deep pipelined loads ----
    if (tid < 224) {
        const int gl = tid / 112;
        const int rem = tid - gl * 112;
        const int c2 = rem / 14, pq = rem - c2 * 14;
        const int g = gp * 2 + gl;
        const int cc0 = c2 * 2;
        const unsigned short* wg = &wgt[gl * 52 * 68 + pq * 4];
        const bool eL = (pq > 0), eR = (pq < 13);
        const int offL = eL ? 0 : 4;            // clamped, always in-bounds
        const int offR = eR ? 8 : 4;
        const float* yb0 = y + (size_t)(b * 256 + g * 16 + cc0) * HWSZ + pq * 4 - 4;
        const float* yb1 = yb0 + HWSZ;

        float4 cA0, cA1, cA2, cB0, cB1, cB2;
        float4 nA0, nA1, nA2, nB0, nB1, nB2;
        {
            const int hs = h - 3;
            const int hsc = hs < 0 ? 0 : hs;
            const float* r0 = yb0 + hsc * WW;
            const float* r1 = yb1 + hsc * WW;
            cA0 = *(const float4*)(r0 + offL);
            cA1 = *(const float4*)(r0 + 4);
            cA2 = *(const float4*)(r0 + offR);
            cB0 = *(const float4*)(r1 + offL);
            cB1 = *(const float4*)(r1 + 4);
            cB2 = *(const float4*)(r1 + offR);
        }
        float a00=0.f,a01=0.f,a02=0.f,a03=0.f;
        float a10=0.f,a11=0.f,a12=0.f,a13=0.f;

        #pragma unroll
        for (int di = 0; di < KS; ++di) {
            if (di < 6) {                       // issue next row's loads first
                const int hs = h - 2 + di;
                const int hsc = hs < 0 ? 0 : (hs > HH - 1 ? HH - 1 : hs);
                const float* r0 = yb0 + hsc * WW;
                const float* r1 = yb1 + hsc * WW;
                nA0 = *(const float4*)(r0 + offL);
                nA1 = *(const float4*)(r0 + 4);
                nA2 = *(const float4*)(r0 + offR);
                nB0 = *(const float4*)(r1 + offL);
                nB1 = *(const float4*)(r1 + 4);
                nB2 = *(const float4*)(r1 + offR);
            }
            const int hs = h - 3 + di;
            if ((unsigned)hs < HH) {            // block-uniform branch
                float w0[11], w1v[11];
                w0[1] = eL ? cA0.y : 0.f;  w0[2] = eL ? cA0.z : 0.f;  w0[3] = eL ? cA0.w : 0.f;
                w0[4] = cA1.x; w0[5] = cA1.y; w0[6] = cA1.z; w0[7] = cA1.w;
                w0[8] = eR ? cA2.x : 0.f;  w0[9] = eR ? cA2.y : 0.f;  w0[10] = eR ? cA2.z : 0.f;
                w1v[1] = eL ? cB0.y : 0.f; w1v[2] = eL ? cB0.z : 0.f; w1v[3] = eL ? cB0.w : 0.f;
                w1v[4] = cB1.x; w1v[5] = cB1.y; w1v[6] = cB1.z; w1v[7] = cB1.w;
                w1v[8] = eR ? cB2.x : 0.f; w1v[9] = eR ? cB2.y : 0.f; w1v[10] = eR ? cB2.z : 0.f;
                #pragma unroll
                for (int dj = 0; dj < KS; ++dj) {
                    uint2 wr = *(const uint2*)&wg[(di * KS + dj) * 68];
                    float g0 = bflo(wr.x), g1 = bfhi(wr.x);
                    float g2 = bflo(wr.y), g3 = bfhi(wr.y);
                    a00 += g0 * w0[dj + 1];  a01 += g1 * w0[dj + 2];
                    a02 += g2 * w0[dj + 3];  a03 += g3 * w0[dj + 4];
                    a10 += g0 * w1v[dj + 1]; a11 += g1 * w1v[dj + 2];
                    a12 += g2 * w1v[dj + 3]; a13 += g3 * w1v[dj + 4];
                }
            }
            if (di < 6) {
                cA0 = nA0; cA1 = nA1; cA2 = nA2;
                cB0 = nB0; cB1 = nB1; cB2 = nB2;
            }
        }
        float* o0 = out + (size_t)(b * 256 + g * 16 + cc0) * HWSZ + h * WW + pq * 4;
        *(float4*)o0 = make_float4(a00, a01, a02, a03);
        *(float4*)(o0 + HWSZ) = make_float4(a10, a11, a12, a13);
    }
}

extern "C" void kernel_launch(void* const* d_in, const int* in_sizes, int n_in,
                              void* d_out, int out_size, void* d_ws, size_t ws_size,
                              hipStream_t stream) {
    const float* x     = (const float*)d_in[0];
    const float* y     = (const float*)d_in[1];
    const float* w1    = (const float*)d_in[2];
    const float* gamma = (const float*)d_in[3];
    const float* beta  = (const float*)d_in[4];
    const float* mean  = (const float*)d_in[5];
    const float* var   = (const float*)d_in[6];
    const float* w2    = (const float*)d_in[7];
    const float* b2    = (const float*)d_in[8];
    float* out = (float*)d_out;

    fused_dynconv<<<1792, 256, 0, stream>>>(x, y, w1, gamma, beta, mean, var, w2, b2, out);
}

// Round 9
// 56.609 us; speedup vs baseline: 1.1178x; 1.1178x over previous
//
#include <hip/hip_runtime.h>

#define HH 56
#define WW 56
#define HWSZ 3136
#define KS 7
#define KK 49

#define XSTR 520   // x_lds: shorts per c-block row (64px*8c + 8 pad)
#define TSTR 72    // t_lds row stride in shorts

typedef __attribute__((ext_vector_type(8))) short short8;
typedef __attribute__((ext_vector_type(4))) float f32x4;

__device__ inline unsigned short f2bf(float f) {
    unsigned u = __builtin_bit_cast(unsigned, f);
    u += 0x7FFF + ((u >> 16) & 1);          // RNE
    return (unsigned short)(u >> 16);
}
__device__ inline unsigned pk2(float a, float b) {   // RNE pack
    return (unsigned)f2bf(a) | ((unsigned)f2bf(b) << 16);
}
__device__ inline unsigned pktr(float lo, float hi) { // truncation pack, 1 v_perm
    return __builtin_amdgcn_perm(__builtin_bit_cast(unsigned, hi),
                                 __builtin_bit_cast(unsigned, lo), 0x07060302u);
}
__device__ inline float bflo(unsigned u) { return __builtin_bit_cast(float, u << 16); }
__device__ inline float bfhi(unsigned u) { return __builtin_bit_cast(float, u & 0xFFFF0000u); }

// ---- prep: w2 -> bf16 [16 g][64 kk-padded][64 k], one group per block ----
__global__ __launch_bounds__(256) void kprep(
    const float* __restrict__ w2, unsigned short* __restrict__ w2p)
{
    const int g = blockIdx.x, tid = threadIdx.x;
    #pragma unroll
    for (int it = 0; it < 16; ++it) {
        const int i = it * 256 + tid;
        const int r = i >> 6, k = i & 63;
        float v = (r < KK) ? w2[(g * KK + r) * 64 + k] : 0.f;
        w2p[(size_t)(g * 64 + r) * 64 + k] = f2bf(v);
    }
}

// ---- single fused kernel: stage x -> GEMM1 (t) -> GEMM2 (wgt) -> dynamic conv ----
// grid 1792; swizzle keeps all 8 group-pair blocks of one (b,h) on ONE XCD.
__global__ __launch_bounds__(256) void fused_dynconv(
    const float* __restrict__ x, const float* __restrict__ y,
    const float* __restrict__ w1, const float* __restrict__ gamma,
    const float* __restrict__ beta, const float* __restrict__ mean,
    const float* __restrict__ var, const unsigned short* __restrict__ w2p,
    const float* __restrict__ b2, float* __restrict__ out)
{
    __shared__ __align__(16) unsigned short lds[32 * XSTR + 64 * TSTR]; // 42.5 KB
    unsigned short* xls = lds;              // [cblk 32][64 px][8 c]
    unsigned short* tls = lds + 32 * XSTR;  // [64 px][64 o] stride TSTR
    unsigned short* wgt = lds;              // [2 gl][52 kk][68 px]; aliases xls

    const int tid = threadIdx.x;
    const int blk = blockIdx.x;
    // bh%8 == blk%8 == XCD id -> the 8 gp-blocks of a bh share one XCD's L2
    const int bh = ((blk >> 6) << 3) | (blk & 7);   // 0..223
    const int gp = (blk >> 3) & 7;
    const int b = bh / HH, h = bh - b * HH;
    const int hw0 = h * WW;

    // ---- phase 0: stage x[64px][256c] -> bf16 LDS (trunc pack) ----
    {
        const int pl = tid & 63, cq = tid >> 6;
        const int hwc = min(hw0 + pl, HWSZ - 1);    // clamp image tail
        const float* xb = x + (size_t)b * 256 * HWSZ + hwc;
        #pragma unroll
        for (int ps = 0; ps < 8; ++ps) {
            const int cb = ps * 4 + cq;
            const int c0 = cb * 8;
            unsigned u[4];
            #pragma unroll
            for (int j = 0; j < 4; ++j) {
                float va = xb[(size_t)(c0 + 2 * j) * HWSZ];
                float vb = xb[(size_t)(c0 + 2 * j + 1) * HWSZ];
                u[j] = pktr(va, vb);
            }
            *(uint4*)&xls[cb * XSTR + pl * 8] = make_uint4(u[0], u[1], u[2], u[3]);
        }
    }

    const int lane = tid & 63, wv = tid >> 6;
    const int m = lane & 15, q = lane >> 4;

    // A-fragments for GEMM1 from global w1 (L1/L2-hot), trunc pack
    short8 af[8];
    {
        const float* wrow = w1 + (wv * 16 + m) * 256 + q * 8;
        #pragma unroll
        for (int ks = 0; ks < 8; ++ks) {
            float4 f0 = *(const float4*)(wrow + ks * 32);
            float4 f1 = *(const float4*)(wrow + ks * 32 + 4);
            uint4 u = make_uint4(pktr(f0.x, f0.y), pktr(f0.z, f0.w),
                                 pktr(f1.x, f1.y), pktr(f1.z, f1.w));
            af[ks] = __builtin_bit_cast(short8, u);
        }
    }
    __syncthreads();

    // ---- phase 1: GEMM1  t[px][o] = relu(BN(x @ w1^T)) ----
    #pragma unroll
    for (int nt = 0; nt < 4; ++nt) {
        f32x4 acc = {0.f, 0.f, 0.f, 0.f};
        #pragma unroll
        for (int ks = 0; ks < 8; ++ks) {
            short8 bfr = *(const short8*)&xls[(ks * 4 + q) * XSTR + (nt * 16 + m) * 8];
            acc = __builtin_amdgcn_mfma_f32_16x16x32_bf16(af[ks], bfr, acc, 0, 0, 0);
        }
        // D: col(lane&15)=px, row((lane>>4)*4+j)=o — verified layout
        const int ob = wv * 16 + q * 4;
        float4 g4 = *(const float4*)&gamma[ob];
        float4 v4 = *(const float4*)&var[ob];
        float4 m4 = *(const float4*)&mean[ob];
        float4 b4 = *(const float4*)&beta[ob];
        float gg[4] = {g4.x, g4.y, g4.z, g4.w};
        float vv[4] = {v4.x, v4.y, v4.z, v4.w};
        float mm[4] = {m4.x, m4.y, m4.z, m4.w};
        float bb[4] = {b4.x, b4.y, b4.z, b4.w};
        float r[4];
        #pragma unroll
        for (int j = 0; j < 4; ++j) {
            float sc = gg[j] * rsqrtf(vv[j] + 1e-5f);
            float sh = bb[j] - mm[j] * sc;
            float val = acc[j] * sc + sh;
            r[j] = val > 0.f ? val : 0.f;
        }
        *(uint2*)&tls[(nt * 16 + m) * TSTR + ob] = make_uint2(pk2(r[0], r[1]), pk2(r[2], r[3]));
    }
    __syncthreads();

    // ---- phase 2: GEMM2  wgt[gl][kk][px] = sum_k t[px][k] * w2p[g][kk][k] + b2 ----
    {
        const int pt = wv;                  // wave = pixel-tile, both groups
        const unsigned short* tp = tls + (pt * 16 + m) * TSTR + q * 8;
        short8 a0 = *(const short8*)tp;            // k = q*8 + 0..7
        short8 a1 = *(const short8*)(tp + 32);     // k = 32 + q*8 + 0..7
        #pragma unroll
        for (int it = 0; it < 2; ++it) {
            const int g = gp * 2 + it;
            f32x4 acc[4];
            #pragma unroll
            for (int mt = 0; mt < 4; ++mt) { acc[mt][0]=0.f; acc[mt][1]=0.f; acc[mt][2]=0.f; acc[mt][3]=0.f; }
            #pragma unroll
            for (int mt = 0; mt < 4; ++mt) {
                const unsigned short* tb = w2p + (size_t)(g * 64 + mt * 16 + m) * 64 + q * 8;
                short8 b0 = *(const short8*)tb;
                short8 b1 = *(const short8*)(tb + 32);
                acc[mt] = __builtin_amdgcn_mfma_f32_16x16x32_bf16(a0, b0, acc[mt], 0, 0, 0);
                acc[mt] = __builtin_amdgcn_mfma_f32_16x16x32_bf16(a1, b1, acc[mt], 0, 0, 0);
            }
            // D: col(kk)=lane&15, row(px)=(lane>>4)*4+j — verified layout
            #pragma unroll
            for (int mt = 0; mt < 4; ++mt) {
                const int kk = mt * 16 + m;
                if (kk < 52) {
                    float bv = (kk < KK) ? b2[g * KK + kk] : 0.f;
                    f32x4 v = acc[mt];
                    const int pxb = pt * 16 + q * 4;
                    *(uint2*)&wgt[(it * 52 + kk) * 68 + pxb] =
                        make_uint2(pk2(v[0] + bv, v[1] + bv), pk2(v[2] + bv, v[3] + bv));
                }
            }
        }
    }
    __syncthreads();

    // ---- phase 3: conv, 2cc x 4px per thread, 1-row-deep pipelined loads ----
    if (tid < 224) {
        const int gl = tid / 112;
        const int rem = tid - gl * 112;
        const int c2 = rem / 14, pq = rem - c2 * 14;
        const int g = gp * 2 + gl;
        const int cc0 = c2 * 2;
        const unsigned short* wg = &wgt[gl * 52 * 68 + pq * 4];
        const bool eL = (pq > 0), eR = (pq < 13);
        const int offL = eL ? 0 : 4;            // clamped, always in-bounds
        const int offR = eR ? 8 : 4;
        const float* yb0 = y + (size_t)(b * 256 + g * 16 + cc0) * HWSZ + pq * 4 - 4;
        const float* yb1 = yb0 + HWSZ;

        float4 cA0, cA1, cA2, cB0, cB1, cB2;
        float4 nA0, nA1, nA2, nB0, nB1, nB2;
        {
            const int hs = h - 3;
            const int hsc = hs < 0 ? 0 : hs;
            const float* r0 = yb0 + hsc * WW;
            const float* r1 = yb1 + hsc * WW;
            cA0 = *(const float4*)(r0 + offL);
            cA1 = *(const float4*)(r0 + 4);
            cA2 = *(const float4*)(r0 + offR);
            cB0 = *(const float4*)(r1 + offL);
            cB1 = *(const float4*)(r1 + 4);
            cB2 = *(const float4*)(r1 + offR);
        }
        float a00=0.f,a01=0.f,a02=0.f,a03=0.f;
        float a10=0.f,a11=0.f,a12=0.f,a13=0.f;

        #pragma unroll
        for (int di = 0; di < KS; ++di) {
            if (di < 6) {                       // issue next row's loads first
                const int hs = h - 2 + di;
                const int hsc = hs < 0 ? 0 : (hs > HH - 1 ? HH - 1 : hs);
                const float* r0 = yb0 + hsc * WW;
                const float* r1 = yb1 + hsc * WW;
                nA0 = *(const float4*)(r0 + offL);
                nA1 = *(const float4*)(r0 + 4);
                nA2 = *(const float4*)(r0 + offR);
                nB0 = *(const float4*)(r1 + offL);
                nB1 = *(const float4*)(r1 + 4);
                nB2 = *(const float4*)(r1 + offR);
            }
            const int hs = h - 3 + di;
            if ((unsigned)hs < HH) {            // block-uniform branch
                float w0[11], w1v[11];
                w0[1] = eL ? cA0.y : 0.f;  w0[2] = eL ? cA0.z : 0.f;  w0[3] = eL ? cA0.w : 0.f;
                w0[4] = cA1.x; w0[5] = cA1.y; w0[6] = cA1.z; w0[7] = cA1.w;
                w0[8] = eR ? cA2.x : 0.f;  w0[9] = eR ? cA2.y : 0.f;  w0[10] = eR ? cA2.z : 0.f;
                w1v[1] = eL ? cB0.y : 0.f; w1v[2] = eL ? cB0.z : 0.f; w1v[3] = eL ? cB0.w : 0.f;
                w1v[4] = cB1.x; w1v[5] = cB1.y; w1v[6] = cB1.z; w1v[7] = cB1.w;
                w1v[8] = eR ? cB2.x : 0.f; w1v[9] = eR ? cB2.y : 0.f; w1v[10] = eR ? cB2.z : 0.f;
                #pragma unroll
                for (int dj = 0; dj < KS; ++dj) {
                    uint2 wr = *(const uint2*)&wg[(di * KS + dj) * 68];
                    float g0 = bflo(wr.x), g1 = bfhi(wr.x);
                    float g2 = bflo(wr.y), g3 = bfhi(wr.y);
                    a00 += g0 * w0[dj + 1];  a01 += g1 * w0[dj + 2];
                    a02 += g2 * w0[dj + 3];  a03 += g3 * w0[dj + 4];
                    a10 += g0 * w1v[dj + 1]; a11 += g1 * w1v[dj + 2];
                    a12 += g2 * w1v[dj + 3]; a13 += g3 * w1v[dj + 4];
                }
            }
            if (di < 6) {
                cA0 = nA0; cA1 = nA1; cA2 = nA2;
                cB0 = nB0; cB1 = nB1; cB2 = nB2;
            }
        }
        float* o0 = out + (size_t)(b * 256 + g * 16 + cc0) * HWSZ + h * WW + pq * 4;
        *(float4*)o0 = make_float4(a00, a01, a02, a03);
        *(float4*)(o0 + HWSZ) = make_float4(a10, a11, a12, a13);
    }
}

extern "C" void kernel_launch(void* const* d_in, const int* in_sizes, int n_in,
                              void* d_out, int out_size, void* d_ws, size_t ws_size,
                              hipStream_t stream) {
    const float* x     = (const float*)d_in[0];
    const float* y     = (const float*)d_in[1];
    const float* w1    = (const float*)d_in[2];
    const float* gamma = (const float*)d_in[3];
    const float* beta  = (const float*)d_in[4];
    const float* mean  = (const float*)d_in[5];
    const float* var   = (const float*)d_in[6];
    const float* w2    = (const float*)d_in[7];
    const float* b2    = (const float*)d_in[8];
    float* out = (float*)d_out;
    unsigned short* w2p = (unsigned short*)d_ws;   // [16*64][64] bf16, 128 KB

    kprep<<<16, 256, 0, stream>>>(w2, w2p);
    fused_dynconv<<<1792, 256, 0, stream>>>(x, y, w1, gamma, beta, mean, var, w2p, b2, out);
}

// Round 10
// 55.601 us; speedup vs baseline: 1.1381x; 1.0181x over previous
//
#include <hip/hip_runtime.h>

#define HH 56
#define WW 56
#define HWSZ 3136
#define KS 7
#define KK 49

#define XSTR 520   // x_lds: shorts per c-block row (64px*8c + 8 pad)
#define TSTR 72    // t_lds row stride in shorts

typedef __attribute__((ext_vector_type(8))) short short8;
typedef __attribute__((ext_vector_type(4))) float f32x4;

__device__ inline unsigned short f2bf(float f) {
    unsigned u = __builtin_bit_cast(unsigned, f);
    u += 0x7FFF + ((u >> 16) & 1);          // RNE
    return (unsigned short)(u >> 16);
}
__device__ inline unsigned pk2(float a, float b) {   // RNE pack
    return (unsigned)f2bf(a) | ((unsigned)f2bf(b) << 16);
}
__device__ inline unsigned pktr(float lo, float hi) { // truncation pack, 1 v_perm
    return __builtin_amdgcn_perm(__builtin_bit_cast(unsigned, hi),
                                 __builtin_bit_cast(unsigned, lo), 0x07060302u);
}
__device__ inline float bflo(unsigned u) { return __builtin_bit_cast(float, u << 16); }
__device__ inline float bfhi(unsigned u) { return __builtin_bit_cast(float, u & 0xFFFF0000u); }

// ---- prep: w2 -> bf16 [16 g][64 kk-padded][64 k], one group per block ----
__global__ __launch_bounds__(256) void kprep(
    const float* __restrict__ w2, unsigned short* __restrict__ w2p)
{
    const int g = blockIdx.x, tid = threadIdx.x;
    #pragma unroll
    for (int it = 0; it < 16; ++it) {
        const int i = it * 256 + tid;
        const int r = i >> 6, k = i & 63;
        float v = (r < KK) ? w2[(g * KK + r) * 64 + k] : 0.f;
        w2p[(size_t)(g * 64 + r) * 64 + k] = f2bf(v);
    }
}

// ---- single fused kernel: stage x -> GEMM1 (t) -> GEMM2 (wgt) -> dynamic conv ----
// grid 1792; chunked swizzle: XCD k owns contiguous (bh,gp) range -> x-tile 8x reuse
// and y 7x vertical reuse are both XCD-L2-local.
__global__ __launch_bounds__(256) void fused_dynconv(
    const float* __restrict__ x, const float* __restrict__ y,
    const float* __restrict__ w1, const float* __restrict__ gamma,
    const float* __restrict__ beta, const float* __restrict__ mean,
    const float* __restrict__ var, const unsigned short* __restrict__ w2p,
    const float* __restrict__ b2, float* __restrict__ out)
{
    __shared__ __align__(16) unsigned short lds[32 * XSTR + 64 * TSTR]; // 42.5 KB
    unsigned short* xls = lds;              // [cblk 32][64 px][8 c]
    unsigned short* tls = lds + 32 * XSTR;  // [64 px][64 o] stride TSTR
    unsigned short* wgt = lds;              // [2 gl][52 kk][68 px]; aliases xls

    const int tid = threadIdx.x;
    // chunked bijective swizzle (assumes XCD = blockIdx % 8 round-robin)
    const int lin = (blockIdx.x & 7) * 224 + (blockIdx.x >> 3);  // 0..1791
    const int bh = lin >> 3;                // 0..223, contiguous per XCD
    const int gp = lin & 7;
    const int b = bh / HH, h = bh - b * HH;
    const int hw0 = h * WW;

    // ---- phase 0: stage x[64px][256c] -> bf16 LDS; 2 batches of 32 loads ----
    {
        const int pl = tid & 63, cq = tid >> 6;
        const int hwc = min(hw0 + pl, HWSZ - 1);    // clamp image tail
        const float* xb = x + (size_t)b * 256 * HWSZ + hwc;
        #pragma unroll
        for (int half = 0; half < 2; ++half) {
            float v[32];
            #pragma unroll
            for (int ps = 0; ps < 4; ++ps) {        // issue 32 loads, no waits between
                const int c0 = ((half * 4 + ps) * 4 + cq) * 8;
                #pragma unroll
                for (int j = 0; j < 8; ++j)
                    v[ps * 8 + j] = xb[(size_t)(c0 + j) * HWSZ];
            }
            #pragma unroll
            for (int ps = 0; ps < 4; ++ps) {        // pack + write
                const int cb = (half * 4 + ps) * 4 + cq;
                uint4 u = make_uint4(pktr(v[ps*8+0], v[ps*8+1]),
                                     pktr(v[ps*8+2], v[ps*8+3]),
                                     pktr(v[ps*8+4], v[ps*8+5]),
                                     pktr(v[ps*8+6], v[ps*8+7]));
                *(uint4*)&xls[cb * XSTR + pl * 8] = u;
            }
        }
    }

    const int lane = tid & 63, wv = tid >> 6;
    const int m = lane & 15, q = lane >> 4;

    // A-fragments for GEMM1 from global w1 (L1/L2-hot), trunc pack
    short8 af[8];
    {
        const float* wrow = w1 + (wv * 16 + m) * 256 + q * 8;
        #pragma unroll
        for (int ks = 0; ks < 8; ++ks) {
            float4 f0 = *(const float4*)(wrow + ks * 32);
            float4 f1 = *(const float4*)(wrow + ks * 32 + 4);
            uint4 u = make_uint4(pktr(f0.x, f0.y), pktr(f0.z, f0.w),
                                 pktr(f1.x, f1.y), pktr(f1.z, f1.w));
            af[ks] = __builtin_bit_cast(short8, u);
        }
    }
    __syncthreads();

    // ---- phase 1: GEMM1  t[px][o] = relu(BN(x @ w1^T)) ----
    #pragma unroll
    for (int nt = 0; nt < 4; ++nt) {
        f32x4 acc = {0.f, 0.f, 0.f, 0.f};
        #pragma unroll
        for (int ks = 0; ks < 8; ++ks) {
            short8 bfr = *(const short8*)&xls[(ks * 4 + q) * XSTR + (nt * 16 + m) * 8];
            acc = __builtin_amdgcn_mfma_f32_16x16x32_bf16(af[ks], bfr, acc, 0, 0, 0);
        }
        // D: col(lane&15)=px, row((lane>>4)*4+j)=o — verified layout
        const int ob = wv * 16 + q * 4;
        float4 g4 = *(const float4*)&gamma[ob];
        float4 v4 = *(const float4*)&var[ob];
        float4 m4 = *(const float4*)&mean[ob];
        float4 b4 = *(const float4*)&beta[ob];
        float gg[4] = {g4.x, g4.y, g4.z, g4.w};
        float vv[4] = {v4.x, v4.y, v4.z, v4.w};
        float mm[4] = {m4.x, m4.y, m4.z, m4.w};
        float bb[4] = {b4.x, b4.y, b4.z, b4.w};
        float r[4];
        #pragma unroll
        for (int j = 0; j < 4; ++j) {
            float sc = gg[j] * rsqrtf(vv[j] + 1e-5f);
            float sh = bb[j] - mm[j] * sc;
            float val = acc[j] * sc + sh;
            r[j] = val > 0.f ? val : 0.f;
        }
        *(uint2*)&tls[(nt * 16 + m) * TSTR + ob] = make_uint2(pk2(r[0], r[1]), pk2(r[2], r[3]));
    }
    __syncthreads();

    // ---- phase 2: GEMM2  wgt[gl][kk][px] = sum_k t[px][k] * w2p[g][kk][k] + b2 ----
    {
        const int pt = wv;                  // wave = pixel-tile, both groups
        const unsigned short* tp = tls + (pt * 16 + m) * TSTR + q * 8;
        short8 a0 = *(const short8*)tp;            // k = q*8 + 0..7
        short8 a1 = *(const short8*)(tp + 32);     // k = 32 + q*8 + 0..7
        #pragma unroll
        for (int it = 0; it < 2; ++it) {
            const int g = gp * 2 + it;
            // hoist all 8 B-fragments (one latency exposure)
            short8 bfr[8];
            #pragma unroll
            for (int mt = 0; mt < 4; ++mt) {
                const unsigned short* tb = w2p + (size_t)(g * 64 + mt * 16 + m) * 64 + q * 8;
                bfr[mt * 2]     = *(const short8*)tb;
                bfr[mt * 2 + 1] = *(const short8*)(tb + 32);
            }
            f32x4 acc[4];
            #pragma unroll
            for (int mt = 0; mt < 4; ++mt) { acc[mt][0]=0.f; acc[mt][1]=0.f; acc[mt][2]=0.f; acc[mt][3]=0.f; }
            #pragma unroll
            for (int mt = 0; mt < 4; ++mt) {
                acc[mt] = __builtin_amdgcn_mfma_f32_16x16x32_bf16(a0, bfr[mt * 2],     acc[mt], 0, 0, 0);
                acc[mt] = __builtin_amdgcn_mfma_f32_16x16x32_bf16(a1, bfr[mt * 2 + 1], acc[mt], 0, 0, 0);
            }
            // D: col(kk)=lane&15, row(px)=(lane>>4)*4+j — verified layout
            #pragma unroll
            for (int mt = 0; mt < 4; ++mt) {
                const int kk = mt * 16 + m;
                if (kk < 52) {
                    float bv = (kk < KK) ? b2[g * KK + kk] : 0.f;
                    f32x4 v = acc[mt];
                    const int pxb = pt * 16 + q * 4;
                    *(uint2*)&wgt[(it * 52 + kk) * 68 + pxb] =
                        make_uint2(pk2(v[0] + bv, v[1] + bv), pk2(v[2] + bv, v[3] + bv));
                }
            }
        }
    }
    __syncthreads();

    // ---- phase 3: conv, 2cc x 4px per thread, 1-row-deep pipelined loads ----
    if (tid < 224) {
        const int gl = tid / 112;
        const int rem = tid - gl * 112;
        const int c2 = rem / 14, pq = rem - c2 * 14;
        const int g = gp * 2 + gl;
        const int cc0 = c2 * 2;
        const unsigned short* wg = &wgt[gl * 52 * 68 + pq * 4];
        const bool eL = (pq > 0), eR = (pq < 13);
        const int offL = eL ? 0 : 4;            // clamped, always in-bounds
        const int offR = eR ? 8 : 4;
        const float* yb0 = y + (size_t)(b * 256 + g * 16 + cc0) * HWSZ + pq * 4 - 4;
        const float* yb1 = yb0 + HWSZ;

        float4 cA0, cA1, cA2, cB0, cB1, cB2;
        float4 nA0, nA1, nA2, nB0, nB1, nB2;
        {
            const int hs = h - 3;
            const int hsc = hs < 0 ? 0 : hs;
            const float* r0 = yb0 + hsc * WW;
            const float* r1 = yb1 + hsc * WW;
            cA0 = *(const float4*)(r0 + offL);
            cA1 = *(const float4*)(r0 + 4);
            cA2 = *(const float4*)(r0 + offR);
            cB0 = *(const float4*)(r1 + offL);
            cB1 = *(const float4*)(r1 + 4);
            cB2 = *(const float4*)(r1 + offR);
        }
        float a00=0.f,a01=0.f,a02=0.f,a03=0.f;
        float a10=0.f,a11=0.f,a12=0.f,a13=0.f;

        #pragma unroll
        for (int di = 0; di < KS; ++di) {
            if (di < 6) {                       // issue next row's loads first
                const int hs = h - 2 + di;
                const int hsc = hs < 0 ? 0 : (hs > HH - 1 ? HH - 1 : hs);
                const float* r0 = yb0 + hsc * WW;
                const float* r1 = yb1 + hsc * WW;
                nA0 = *(const float4*)(r0 + offL);
                nA1 = *(const float4*)(r0 + 4);
                nA2 = *(const float4*)(r0 + offR);
                nB0 = *(const float4*)(r1 + offL);
                nB1 = *(const float4*)(r1 + 4);
                nB2 = *(const float4*)(r1 + offR);
            }
            const int hs = h - 3 + di;
            if ((unsigned)hs < HH) {            // block-uniform branch
                float w0[11], w1v[11];
                w0[1] = eL ? cA0.y : 0.f;  w0[2] = eL ? cA0.z : 0.f;  w0[3] = eL ? cA0.w : 0.f;
                w0[4] = cA1.x; w0[5] = cA1.y; w0[6] = cA1.z; w0[7] = cA1.w;
                w0[8] = eR ? cA2.x : 0.f;  w0[9] = eR ? cA2.y : 0.f;  w0[10] = eR ? cA2.z : 0.f;
                w1v[1] = eL ? cB0.y : 0.f; w1v[2] = eL ? cB0.z : 0.f; w1v[3] = eL ? cB0.w : 0.f;
                w1v[4] = cB1.x; w1v[5] = cB1.y; w1v[6] = cB1.z; w1v[7] = cB1.w;
                w1v[8] = eR ? cB2.x : 0.f; w1v[9] = eR ? cB2.y : 0.f; w1v[10] = eR ? cB2.z : 0.f;
                #pragma unroll
                for (int dj = 0; dj < KS; ++dj) {
                    uint2 wr = *(const uint2*)&wg[(di * KS + dj) * 68];
                    float g0 = bflo(wr.x), g1 = bfhi(wr.x);
                    float g2 = bflo(wr.y), g3 = bfhi(wr.y);
                    a00 += g0 * w0[dj + 1];  a01 += g1 * w0[dj + 2];
                    a02 += g2 * w0[dj + 3];  a03 += g3 * w0[dj + 4];
                    a10 += g0 * w1v[dj + 1]; a11 += g1 * w1v[dj + 2];
                    a12 += g2 * w1v[dj + 3]; a13 += g3 * w1v[dj + 4];
                }
            }
            if (di < 6) {
                cA0 = nA0; cA1 = nA1; cA2 = nA2;
                cB0 = nB0; cB1 = nB1; cB2 = nB2;
            }
        }
        float* o0 = out + (size_t)(b * 256 + g * 16 + cc0) * HWSZ + h * WW + pq * 4;
        *(float4*)o0 = make_float4(a00, a01, a02, a03);
        *(float4*)(o0 + HWSZ) = make_float4(a10, a11, a12, a13);
    }
}

extern "C" void kernel_launch(void* const* d_in, const int* in_sizes, int n_in,
                              void* d_out, int out_size, void* d_ws, size_t ws_size,
                              hipStream_t stream) {
    const float* x     = (const float*)d_in[0];
    const float* y     = (const float*)d_in[1];
    const float* w1    = (const float*)d_in[2];
    const float* gamma = (const float*)d_in[3];
    const float* beta  = (const float*)d_in[4];
    const float* mean  = (const float*)d_in[5];
    const float* var   = (const float*)d_in[6];
    const float* w2    = (const float*)d_in[7];
    const float* b2    = (const float*)d_in[8];
    float* out = (float*)d_out;
    unsigned short* w2p = (unsigned short*)d_ws;   // [16*64][64] bf16, 128 KB

    kprep<<<16, 256, 0, stream>>>(w2, w2p);
    fused_dynconv<<<1792, 256, 0, stream>>>(x, y, w1, gamma, beta, mean, var, w2p, b2, out);
}